// Round 9
// baseline (73.712 us; speedup 1.0000x reference)
//
#include <hip/hip_runtime.h>

#define N_LC 4194304
#define T_STEPS 20
#define BLOCK 256
#define VEC 4                         // floats per thread (one float4) -- R5/R7-proven
#define GRID (N_LC / (BLOCK * VEC))   // 4096 blocks
#define TB 4                          // timestep batch (software pipeline depth)

// Resident split (R5-proven 16/32): even blocks keep noise cache-resident
// (0.5*335.5MB + 50MB states = 218MB < 256MB L3); odd blocks stream noise
// nontemporally from HBM.
typedef float vfloat4 __attribute__((ext_vector_type(4)));

__device__ __forceinline__ vfloat4 ld4(const float* p) {
    return *reinterpret_cast<const vfloat4*>(p);
}
__device__ __forceinline__ vfloat4 ld4nt(const float* p) {
    return __builtin_nontemporal_load(reinterpret_cast<const vfloat4*>(p));
}

// ---------------------------------------------------------------------------
// Sim kernel: R7 structure + batch-4 software-pipelined noise loads:
// issue loads for steps [4b+4, 4b+8) BEFORE computing steps [4b, 4b+4),
// guaranteeing 4-8 outstanding loads per wave (latency -> bandwidth bound).
// FMA-minimized body (~12 VALU/neuron-step). Partial sums; no atomics/memset.
// ---------------------------------------------------------------------------
template <bool RESIDENT>
__device__ __forceinline__ void sim_body(
    const float* __restrict__ amygdala,
    const float* __restrict__ insula,
    const float* __restrict__ circadian,
    const float* __restrict__ cms,
    const float* __restrict__ v0,
    const float* __restrict__ u0,
    const float* __restrict__ rate0,
    const float* __restrict__ noise,
    float* __restrict__ ws_partial)
{
    const size_t base = (size_t)(blockIdx.x * BLOCK + threadIdx.x) * VEC;

    const float tonic  = 2.0f + circadian[0] * 3.0f + insula[0] * 5.0f + cms[0] * 3.0f;
    const float phasic = (amygdala[0] > 0.3f) ? 15.0f : 0.0f;
    const float Iconst140 = tonic + phasic + 0.5f + 140.0f;   // 140 + I folded

    float v[VEC], u[VEC], r[VEC];
    {
        const vfloat4 vv = ld4(v0 + base);
        const vfloat4 uu = ld4(u0 + base);
        const vfloat4 rr = ld4(rate0 + base);
        #pragma unroll
        for (int i = 0; i < VEC; ++i) { v[i] = vv[i]; u[i] = uu[i]; r[i] = rr[i]; }
    }

    auto ldn = [&](int t) -> vfloat4 {
        const float* p = noise + (size_t)t * N_LC + base;
        return RESIDENT ? ld4(p) : ld4nt(p);
    };

    auto step4 = [&](const vfloat4 nn) {
        #pragma unroll
        for (int i = 0; i < VEC; ++i) {
            float vv = v[i], uu = u[i];
            const float w = fmaf(0.5f, nn[i], Iconst140) - uu;     // 140+I-u
            vv = fmaf(vv, fmaf(0.04f, vv, 6.0f), w);               // 0.04v^2+6v+w
            uu = fmaf(0.02f, fmaf(0.2f, vv, -uu), uu);             // u += a(bv-u)
            const bool sp = (vv >= 30.0f);
            v[i] = sp ? -65.0f : vv;
            u[i] = sp ? (uu + 8.0f) : uu;
            r[i] = fmaf(0.9f, r[i], sp ? 0.1f : 0.0f);
        }
    };

    // Prologue: loads for steps 0..3 in flight.
    vfloat4 nbuf[TB];
    #pragma unroll
    for (int j = 0; j < TB; ++j) nbuf[j] = ldn(j);

    #pragma unroll
    for (int tb = 0; tb < T_STEPS / TB; ++tb) {
        vfloat4 nnext[TB];
        if (tb + 1 < T_STEPS / TB) {          // issue NEXT batch's loads first
            #pragma unroll
            for (int j = 0; j < TB; ++j) nnext[j] = ldn((tb + 1) * TB + j);
        }
        #pragma unroll
        for (int j = 0; j < TB; ++j) step4(nbuf[j]);   // compute CURRENT batch
        #pragma unroll
        for (int j = 0; j < TB; ++j) nbuf[j] = nnext[j];
    }

    float rsum = (r[0] + r[1]) + (r[2] + r[3]);
    #pragma unroll
    for (int off = 32; off > 0; off >>= 1)
        rsum += __shfl_down(rsum, off, 64);

    __shared__ float wave_sum[BLOCK / 64];
    const int lane = threadIdx.x & 63;
    const int wid  = threadIdx.x >> 6;
    if (lane == 0) wave_sum[wid] = rsum;
    __syncthreads();
    if (threadIdx.x == 0) {
        float bsum = 0.0f;
        #pragma unroll
        for (int w = 0; w < BLOCK / 64; ++w) bsum += wave_sum[w];
        ws_partial[blockIdx.x] = bsum;               // every slot written every call
    }
}

__global__ __launch_bounds__(BLOCK) void lc_sim_kernel(
    const float* __restrict__ amygdala,
    const float* __restrict__ insula,
    const float* __restrict__ circadian,
    const float* __restrict__ cms,
    const float* __restrict__ v0,
    const float* __restrict__ u0,
    const float* __restrict__ rate0,
    const float* __restrict__ noise,
    float* __restrict__ ws_partial)
{
    if ((blockIdx.x & 1) == 0) {
        sim_body<true >(amygdala, insula, circadian, cms, v0, u0, rate0, noise, ws_partial);
    } else {
        sim_body<false>(amygdala, insula, circadian, cms, v0, u0, rate0, noise, ws_partial);
    }
}

// ---------------------------------------------------------------------------
// Finalize: reduce 4096 partials (1 block of 256), then scalar NA readout.
// ---------------------------------------------------------------------------
__global__ __launch_bounds__(BLOCK) void lc_finalize_kernel(
    const float* __restrict__ ws_partial,
    const float* __restrict__ amygdala,
    float* __restrict__ out)
{
    float s = 0.0f;
    #pragma unroll
    for (int i = 0; i < GRID / BLOCK; ++i)           // 16 strided reads/thread
        s += ws_partial[i * BLOCK + threadIdx.x];

    #pragma unroll
    for (int off = 32; off > 0; off >>= 1)
        s += __shfl_down(s, off, 64);

    __shared__ float wave_sum[BLOCK / 64];
    const int lane = threadIdx.x & 63;
    const int wid  = threadIdx.x >> 6;
    if (lane == 0) wave_sum[wid] = s;
    __syncthreads();
    if (threadIdx.x == 0) {
        float total = 0.0f;
        #pragma unroll
        for (int w = 0; w < BLOCK / 64; ++w) total += wave_sum[w];

        const float lc_mean = total / (float)N_LC;
        float raw_na = fminf(fmaxf(lc_mean * 6.0f, 0.0f), 1.0f);
        if (amygdala[0] > 0.3f) raw_na = fminf(raw_na, 0.8f);
        const float na_ema = 0.85f * 0.3f + 0.15f * raw_na;
        const float na = fminf(fmaxf(na_ema, 0.05f), 0.95f);
        out[0] = na;
        out[1] = lc_mean;
        out[2] = fminf(na * 2.0f, 1.0f);
        out[3] = fminf(na * 1.5f, 1.0f);
    }
}

extern "C" void kernel_launch(void* const* d_in, const int* in_sizes, int n_in,
                              void* d_out, int out_size, void* d_ws, size_t ws_size,
                              hipStream_t stream) {
    const float* amygdala  = (const float*)d_in[0];
    const float* insula    = (const float*)d_in[1];
    const float* circadian = (const float*)d_in[2];
    const float* cms       = (const float*)d_in[3];
    const float* v0        = (const float*)d_in[4];
    const float* u0        = (const float*)d_in[5];
    const float* rate0     = (const float*)d_in[6];
    const float* noise     = (const float*)d_in[7];
    float* out             = (float*)d_out;
    float* ws_partial      = (float*)d_ws;           // GRID floats = 16 KB

    lc_sim_kernel<<<GRID, BLOCK, 0, stream>>>(
        amygdala, insula, circadian, cms, v0, u0, rate0, noise, ws_partial);

    lc_finalize_kernel<<<1, BLOCK, 0, stream>>>(ws_partial, amygdala, out);
}

// Round 10
// 71.996 us; speedup vs baseline: 1.0238x; 1.0238x over previous
//
#include <hip/hip_runtime.h>

#define N_LC 4194304
#define T_STEPS 20
#define BLOCK 256
#define VEC 4                         // floats per thread (one float4) -- R5/R7-proven
#define GRID (N_LC / (BLOCK * VEC))   // 4096 blocks

// Resident split (R5-proven 16/32): even blocks keep noise cache-resident
// (0.5*335.5MB + 50MB states = 218MB < 256MB L3); odd blocks stream noise
// nontemporally from HBM.
typedef float vfloat4 __attribute__((ext_vector_type(4)));

__device__ __forceinline__ vfloat4 ld4(const float* p) {
    return *reinterpret_cast<const vfloat4*>(p);
}
__device__ __forceinline__ vfloat4 ld4nt(const float* p) {
    return __builtin_nontemporal_load(reinterpret_cast<const vfloat4*>(p));
}

// ---------------------------------------------------------------------------
// Sim kernel: R7 structure + depth-1 rolling noise prefetch. VEC=4 live set
// (v,u,r=12 + ncur/nnext=8 + addressing ~10) fits the 64-VGPR budget that
// __launch_bounds__(256,8) pins, giving 8 waves/SIMD AND >=1 load in flight
// per wave (~16 outstanding/SIMD vs 500-900cy load latency).
// FMA-minimized body (~12 VALU/neuron-step). Partial sums; no atomics/memset.
// ---------------------------------------------------------------------------
template <bool RESIDENT>
__device__ __forceinline__ void sim_body(
    const float* __restrict__ amygdala,
    const float* __restrict__ insula,
    const float* __restrict__ circadian,
    const float* __restrict__ cms,
    const float* __restrict__ v0,
    const float* __restrict__ u0,
    const float* __restrict__ rate0,
    const float* __restrict__ noise,
    float* __restrict__ ws_partial)
{
    const size_t base = (size_t)(blockIdx.x * BLOCK + threadIdx.x) * VEC;

    const float tonic  = 2.0f + circadian[0] * 3.0f + insula[0] * 5.0f + cms[0] * 3.0f;
    const float phasic = (amygdala[0] > 0.3f) ? 15.0f : 0.0f;
    const float Iconst140 = tonic + phasic + 0.5f + 140.0f;   // 140 + I folded

    float v[VEC], u[VEC], r[VEC];
    {
        const vfloat4 vv = ld4(v0 + base);
        const vfloat4 uu = ld4(u0 + base);
        const vfloat4 rr = ld4(rate0 + base);
        #pragma unroll
        for (int i = 0; i < VEC; ++i) { v[i] = vv[i]; u[i] = uu[i]; r[i] = rr[i]; }
    }

    auto ldn = [&](int t) -> vfloat4 {
        const float* p = noise + (size_t)t * N_LC + base;
        return RESIDENT ? ld4(p) : ld4nt(p);
    };

    vfloat4 ncur = ldn(0);                       // prefetch t=0

    #pragma unroll
    for (int t = 0; t < T_STEPS; ++t) {
        vfloat4 nnext;
        if (t + 1 < T_STEPS) nnext = ldn(t + 1); // issue next load first

        #pragma unroll
        for (int i = 0; i < VEC; ++i) {
            float vv = v[i], uu = u[i];
            const float w = fmaf(0.5f, ncur[i], Iconst140) - uu;   // 140+I-u
            vv = fmaf(vv, fmaf(0.04f, vv, 6.0f), w);               // 0.04v^2+6v+w
            uu = fmaf(0.02f, fmaf(0.2f, vv, -uu), uu);             // u += a(bv-u)
            const bool sp = (vv >= 30.0f);
            v[i] = sp ? -65.0f : vv;
            u[i] = sp ? (uu + 8.0f) : uu;
            r[i] = fmaf(0.9f, r[i], sp ? 0.1f : 0.0f);
        }
        ncur = nnext;
    }

    float rsum = (r[0] + r[1]) + (r[2] + r[3]);
    #pragma unroll
    for (int off = 32; off > 0; off >>= 1)
        rsum += __shfl_down(rsum, off, 64);

    __shared__ float wave_sum[BLOCK / 64];
    const int lane = threadIdx.x & 63;
    const int wid  = threadIdx.x >> 6;
    if (lane == 0) wave_sum[wid] = rsum;
    __syncthreads();
    if (threadIdx.x == 0) {
        float bsum = 0.0f;
        #pragma unroll
        for (int w = 0; w < BLOCK / 64; ++w) bsum += wave_sum[w];
        ws_partial[blockIdx.x] = bsum;               // every slot written every call
    }
}

__global__ __launch_bounds__(BLOCK, 8) void lc_sim_kernel(
    const float* __restrict__ amygdala,
    const float* __restrict__ insula,
    const float* __restrict__ circadian,
    const float* __restrict__ cms,
    const float* __restrict__ v0,
    const float* __restrict__ u0,
    const float* __restrict__ rate0,
    const float* __restrict__ noise,
    float* __restrict__ ws_partial)
{
    if ((blockIdx.x & 1) == 0) {
        sim_body<true >(amygdala, insula, circadian, cms, v0, u0, rate0, noise, ws_partial);
    } else {
        sim_body<false>(amygdala, insula, circadian, cms, v0, u0, rate0, noise, ws_partial);
    }
}

// ---------------------------------------------------------------------------
// Finalize: reduce 4096 partials (1 block of 256), then scalar NA readout.
// ---------------------------------------------------------------------------
__global__ __launch_bounds__(BLOCK) void lc_finalize_kernel(
    const float* __restrict__ ws_partial,
    const float* __restrict__ amygdala,
    float* __restrict__ out)
{
    float s = 0.0f;
    #pragma unroll
    for (int i = 0; i < GRID / BLOCK; ++i)           // 16 strided reads/thread
        s += ws_partial[i * BLOCK + threadIdx.x];

    #pragma unroll
    for (int off = 32; off > 0; off >>= 1)
        s += __shfl_down(s, off, 64);

    __shared__ float wave_sum[BLOCK / 64];
    const int lane = threadIdx.x & 63;
    const int wid  = threadIdx.x >> 6;
    if (lane == 0) wave_sum[wid] = s;
    __syncthreads();
    if (threadIdx.x == 0) {
        float total = 0.0f;
        #pragma unroll
        for (int w = 0; w < BLOCK / 64; ++w) total += wave_sum[w];

        const float lc_mean = total / (float)N_LC;
        float raw_na = fminf(fmaxf(lc_mean * 6.0f, 0.0f), 1.0f);
        if (amygdala[0] > 0.3f) raw_na = fminf(raw_na, 0.8f);
        const float na_ema = 0.85f * 0.3f + 0.15f * raw_na;
        const float na = fminf(fmaxf(na_ema, 0.05f), 0.95f);
        out[0] = na;
        out[1] = lc_mean;
        out[2] = fminf(na * 2.0f, 1.0f);
        out[3] = fminf(na * 1.5f, 1.0f);
    }
}

extern "C" void kernel_launch(void* const* d_in, const int* in_sizes, int n_in,
                              void* d_out, int out_size, void* d_ws, size_t ws_size,
                              hipStream_t stream) {
    const float* amygdala  = (const float*)d_in[0];
    const float* insula    = (const float*)d_in[1];
    const float* circadian = (const float*)d_in[2];
    const float* cms       = (const float*)d_in[3];
    const float* v0        = (const float*)d_in[4];
    const float* u0        = (const float*)d_in[5];
    const float* rate0     = (const float*)d_in[6];
    const float* noise     = (const float*)d_in[7];
    float* out             = (float*)d_out;
    float* ws_partial      = (float*)d_ws;           // GRID floats = 16 KB

    lc_sim_kernel<<<GRID, BLOCK, 0, stream>>>(
        amygdala, insula, circadian, cms, v0, u0, rate0, noise, ws_partial);

    lc_finalize_kernel<<<1, BLOCK, 0, stream>>>(ws_partial, amygdala, out);
}

// Round 11
// 68.487 us; speedup vs baseline: 1.0763x; 1.0512x over previous
//
#include <hip/hip_runtime.h>

#define N_LC 4194304
#define T_STEPS 20
#define BLOCK 256
#define VEC 4                         // floats per thread (one float4) -- proven
#define GRID (N_LC / (BLOCK * VEC))   // 4096 blocks

// Resident split: blocks with (blockIdx.x % 32) < 23 keep their noise
// cache-resident (23/32 * 335.5MB = 241MB < 256MB L3); the other 9/32
// stream noise nontemporally. States (50MB) are ALSO streamed NT now --
// they are single-touch per replay and must not evict resident noise.
#define RES_MOD 32
#define RES_CUT 23

typedef float vfloat4 __attribute__((ext_vector_type(4)));

__device__ __forceinline__ vfloat4 ld4(const float* p) {
    return *reinterpret_cast<const vfloat4*>(p);
}
__device__ __forceinline__ vfloat4 ld4nt(const float* p) {
    return __builtin_nontemporal_load(reinterpret_cast<const vfloat4*>(p));
}

// ---------------------------------------------------------------------------
// Sim kernel: R7/R9 structure (VEC=4, depth-1 rolling prefetch, fma body,
// __launch_bounds__(256,8) pinning 8 waves/SIMD) with re-balanced L3 split:
// more noise resident, states streamed NT. Partial sums; no atomics/memset.
// ---------------------------------------------------------------------------
template <bool RESIDENT>
__device__ __forceinline__ void sim_body(
    const float* __restrict__ amygdala,
    const float* __restrict__ insula,
    const float* __restrict__ circadian,
    const float* __restrict__ cms,
    const float* __restrict__ v0,
    const float* __restrict__ u0,
    const float* __restrict__ rate0,
    const float* __restrict__ noise,
    float* __restrict__ ws_partial)
{
    const size_t base = (size_t)(blockIdx.x * BLOCK + threadIdx.x) * VEC;

    const float tonic  = 2.0f + circadian[0] * 3.0f + insula[0] * 5.0f + cms[0] * 3.0f;
    const float phasic = (amygdala[0] > 0.3f) ? 15.0f : 0.0f;
    const float Iconst140 = tonic + phasic + 0.5f + 140.0f;   // 140 + I folded

    float v[VEC], u[VEC], r[VEC];
    {
        // Single-touch per replay: stream NT, don't pollute the resident set.
        const vfloat4 vv = ld4nt(v0 + base);
        const vfloat4 uu = ld4nt(u0 + base);
        const vfloat4 rr = ld4nt(rate0 + base);
        #pragma unroll
        for (int i = 0; i < VEC; ++i) { v[i] = vv[i]; u[i] = uu[i]; r[i] = rr[i]; }
    }

    auto ldn = [&](int t) -> vfloat4 {
        const float* p = noise + (size_t)t * N_LC + base;
        return RESIDENT ? ld4(p) : ld4nt(p);
    };

    vfloat4 ncur = ldn(0);                       // prefetch t=0

    #pragma unroll
    for (int t = 0; t < T_STEPS; ++t) {
        vfloat4 nnext;
        if (t + 1 < T_STEPS) nnext = ldn(t + 1); // issue next load first

        #pragma unroll
        for (int i = 0; i < VEC; ++i) {
            float vv = v[i], uu = u[i];
            const float w = fmaf(0.5f, ncur[i], Iconst140) - uu;   // 140+I-u
            vv = fmaf(vv, fmaf(0.04f, vv, 6.0f), w);               // 0.04v^2+6v+w
            uu = fmaf(0.02f, fmaf(0.2f, vv, -uu), uu);             // u += a(bv-u)
            const bool sp = (vv >= 30.0f);
            v[i] = sp ? -65.0f : vv;
            u[i] = sp ? (uu + 8.0f) : uu;
            r[i] = fmaf(0.9f, r[i], sp ? 0.1f : 0.0f);
        }
        ncur = nnext;
    }

    float rsum = (r[0] + r[1]) + (r[2] + r[3]);
    #pragma unroll
    for (int off = 32; off > 0; off >>= 1)
        rsum += __shfl_down(rsum, off, 64);

    __shared__ float wave_sum[BLOCK / 64];
    const int lane = threadIdx.x & 63;
    const int wid  = threadIdx.x >> 6;
    if (lane == 0) wave_sum[wid] = rsum;
    __syncthreads();
    if (threadIdx.x == 0) {
        float bsum = 0.0f;
        #pragma unroll
        for (int w = 0; w < BLOCK / 64; ++w) bsum += wave_sum[w];
        ws_partial[blockIdx.x] = bsum;               // every slot written every call
    }
}

__global__ __launch_bounds__(BLOCK, 8) void lc_sim_kernel(
    const float* __restrict__ amygdala,
    const float* __restrict__ insula,
    const float* __restrict__ circadian,
    const float* __restrict__ cms,
    const float* __restrict__ v0,
    const float* __restrict__ u0,
    const float* __restrict__ rate0,
    const float* __restrict__ noise,
    float* __restrict__ ws_partial)
{
    if ((blockIdx.x % RES_MOD) < RES_CUT) {
        sim_body<true >(amygdala, insula, circadian, cms, v0, u0, rate0, noise, ws_partial);
    } else {
        sim_body<false>(amygdala, insula, circadian, cms, v0, u0, rate0, noise, ws_partial);
    }
}

// ---------------------------------------------------------------------------
// Finalize: reduce 4096 partials (1 block of 256), then scalar NA readout.
// ---------------------------------------------------------------------------
__global__ __launch_bounds__(BLOCK) void lc_finalize_kernel(
    const float* __restrict__ ws_partial,
    const float* __restrict__ amygdala,
    float* __restrict__ out)
{
    float s = 0.0f;
    #pragma unroll
    for (int i = 0; i < GRID / BLOCK; ++i)           // 16 strided reads/thread
        s += ws_partial[i * BLOCK + threadIdx.x];

    #pragma unroll
    for (int off = 32; off > 0; off >>= 1)
        s += __shfl_down(s, off, 64);

    __shared__ float wave_sum[BLOCK / 64];
    const int lane = threadIdx.x & 63;
    const int wid  = threadIdx.x >> 6;
    if (lane == 0) wave_sum[wid] = s;
    __syncthreads();
    if (threadIdx.x == 0) {
        float total = 0.0f;
        #pragma unroll
        for (int w = 0; w < BLOCK / 64; ++w) total += wave_sum[w];

        const float lc_mean = total / (float)N_LC;
        float raw_na = fminf(fmaxf(lc_mean * 6.0f, 0.0f), 1.0f);
        if (amygdala[0] > 0.3f) raw_na = fminf(raw_na, 0.8f);
        const float na_ema = 0.85f * 0.3f + 0.15f * raw_na;
        const float na = fminf(fmaxf(na_ema, 0.05f), 0.95f);
        out[0] = na;
        out[1] = lc_mean;
        out[2] = fminf(na * 2.0f, 1.0f);
        out[3] = fminf(na * 1.5f, 1.0f);
    }
}

extern "C" void kernel_launch(void* const* d_in, const int* in_sizes, int n_in,
                              void* d_out, int out_size, void* d_ws, size_t ws_size,
                              hipStream_t stream) {
    const float* amygdala  = (const float*)d_in[0];
    const float* insula    = (const float*)d_in[1];
    const float* circadian = (const float*)d_in[2];
    const float* cms       = (const float*)d_in[3];
    const float* v0        = (const float*)d_in[4];
    const float* u0        = (const float*)d_in[5];
    const float* rate0     = (const float*)d_in[6];
    const float* noise     = (const float*)d_in[7];
    float* out             = (float*)d_out;
    float* ws_partial      = (float*)d_ws;           // GRID floats = 16 KB

    lc_sim_kernel<<<GRID, BLOCK, 0, stream>>>(
        amygdala, insula, circadian, cms, v0, u0, rate0, noise, ws_partial);

    lc_finalize_kernel<<<1, BLOCK, 0, stream>>>(ws_partial, amygdala, out);
}